// Round 4
// baseline (431.324 us; speedup 1.0000x reference)
//
#include <hip/hip_runtime.h>
#include <math.h>

#define N_NODES 50000
#define EDGES   1250000
#define DIM     64
#define NLAYER  3
#define BATCH   4096

#define NBUCK 196   // coarse buckets: bucket = row >> 8 (256 rows each)
#define RPB   256   // rows per bucket
#define NABLK 128   // phase-A blocks

// ---------------- Phase A1: per-block bucket histogram ----------------

__global__ __launch_bounds__(256) void bucket_hist_kernel(const int* __restrict__ rows,
                                                          int* __restrict__ bhist) {
    __shared__ int h[NBUCK];
    for (int i = threadIdx.x; i < NBUCK; i += 256) h[i] = 0;
    __syncthreads();
    int per = (EDGES + NABLK - 1) / NABLK;
    int e0 = blockIdx.x * per;
    int e1 = min(e0 + per, EDGES);
    for (int e = e0 + threadIdx.x; e < e1; e += 256)
        atomicAdd(&h[rows[e] >> 8], 1);
    __syncthreads();
    for (int i = threadIdx.x; i < NBUCK; i += 256)
        bhist[i * NABLK + blockIdx.x] = h[i];
}

// ---------------- Phase A2: exclusive scan of bhist (bucket-major) ----------------

__global__ __launch_bounds__(1024) void bucket_scan_kernel(const int* __restrict__ bhist,
                                                           int* __restrict__ boffs) {
    __shared__ int wsum[16];
    __shared__ int carry_s;
    int tid = threadIdx.x, lane = tid & 63, wid = tid >> 6;
    if (tid == 0) carry_s = 0;
    __syncthreads();
    const int TOTAL = NBUCK * NABLK;
    for (int basei = 0; basei < TOTAL; basei += 1024) {
        int i = basei + tid;
        int v = (i < TOTAL) ? bhist[i] : 0;
        int s = v;
#pragma unroll
        for (int off = 1; off < 64; off <<= 1) {
            int t = __shfl_up(s, off);
            if (lane >= off) s += t;
        }
        if (lane == 63) wsum[wid] = s;
        __syncthreads();
        if (wid == 0) {
            int xv = (lane < 16) ? wsum[lane] : 0;
#pragma unroll
            for (int off = 1; off < 16; off <<= 1) {
                int t = __shfl_up(xv, off);
                if (lane >= off) xv += t;
            }
            if (lane < 16) wsum[lane] = xv;
        }
        __syncthreads();
        int woff = wid ? wsum[wid - 1] : 0;
        int carry = carry_s;
        if (i < TOTAL) boffs[i] = carry + woff + s - v;
        __syncthreads();
        if (tid == 1023) carry_s = carry + woff + s;
        __syncthreads();
    }
}

// ---------------- Phase A3: scatter edges into bucket staging ----------------

__global__ __launch_bounds__(256) void bucket_scatter_kernel(const int* __restrict__ rows,
                                                             const int* __restrict__ cols,
                                                             const float* __restrict__ vals,
                                                             const int* __restrict__ boffs,
                                                             int2* __restrict__ staging) {
    __shared__ int cur[NBUCK];
    for (int i = threadIdx.x; i < NBUCK; i += 256)
        cur[i] = boffs[i * NABLK + blockIdx.x];
    __syncthreads();
    int per = (EDGES + NABLK - 1) / NABLK;
    int e0 = blockIdx.x * per;
    int e1 = min(e0 + per, EDGES);
    for (int e = e0 + threadIdx.x; e < e1; e += 256) {
        int r = rows[e];
        int p = atomicAdd(&cur[r >> 8], 1);
        staging[p] = make_int2(((r & 255) << 16) | cols[e], __float_as_int(vals[e]));
    }
}

// ---------------- Phase B: per-bucket row_ptr + final CSR ----------------

__global__ __launch_bounds__(256) void csr_build_kernel(const int* __restrict__ boffs,
                                                        const int2* __restrict__ staging,
                                                        int* __restrict__ row_ptr,
                                                        int2* __restrict__ csr) {
    __shared__ int rcur[RPB];
    __shared__ int wred[4];
    int b = blockIdx.x;
    int base = boffs[b * NABLK];
    int end = (b == NBUCK - 1) ? EDGES : boffs[(b + 1) * NABLK];
    int tid = threadIdx.x;
    rcur[tid] = 0;
    __syncthreads();
    for (int p = base + tid; p < end; p += 256)
        atomicAdd(&rcur[staging[p].x >> 16], 1);
    __syncthreads();
    int lane = tid & 63, wid = tid >> 6;
    int v = rcur[tid];
    int s = v;
#pragma unroll
    for (int off = 1; off < 64; off <<= 1) {
        int t = __shfl_up(s, off);
        if (lane >= off) s += t;
    }
    if (lane == 63) wred[wid] = s;
    __syncthreads();
    if (tid == 0) {
        int a = 0;
#pragma unroll
        for (int i = 0; i < 4; ++i) { int t = wred[i]; wred[i] = a; a += t; }
    }
    __syncthreads();
    int excl = wred[wid] + s - v;
    __syncthreads();
    rcur[tid] = base + excl;
    int row = b * RPB + tid;
    if (row < N_NODES) row_ptr[row] = base + excl;
    if (b == NBUCK - 1 && tid == 0) row_ptr[N_NODES] = EDGES;
    __syncthreads();
    for (int p = base + tid; p < end; p += 256) {
        int2 e = staging[p];
        int pos = atomicAdd(&rcur[e.x >> 16], 1);
        csr[pos] = make_int2(e.x & 0xFFFF, e.y);
    }
}

// ---------------- W transpose: w?T[l][j][d] = w?[l][d][j] ----------------

__global__ __launch_bounds__(256) void transpose_w_kernel(const float* __restrict__ w1,
                                                          const float* __restrict__ w2,
                                                          float* __restrict__ w1T,
                                                          float* __restrict__ w2T) {
    int i = blockIdx.x * 256 + threadIdx.x;
    if (i >= NLAYER * DIM * DIM) return;
    int l = i >> 12, r = i & 4095;
    int d = r >> 6, j = r & 63;
    w1T[l * 4096 + j * 64 + d] = w1[i];
    w2T[l * 4096 + j * 64 + d] = w2[i];
}

// ---------------- SpMM: one wave per row, 4 edge-groups x 16 lanes x float4 ----

__global__ __launch_bounds__(256) void spmm_kernel(const int* __restrict__ row_ptr,
                                                   const int2* __restrict__ csr,
                                                   const float* __restrict__ x,
                                                   float* __restrict__ agg) {
    int lane = threadIdx.x & 63;
    int g = lane >> 4;
    int sl = lane & 15;
    int row = blockIdx.x * 4 + (threadIdx.x >> 6);
    if (row >= N_NODES) return;
    int p0 = row_ptr[row], p1 = row_ptr[row + 1];
    float4 acc = make_float4(0.f, 0.f, 0.f, 0.f);
    int p = p0;
    for (; p + 16 <= p1; p += 16) {
        int2 a = csr[p + g];
        int2 b = csr[p + 4 + g];
        int2 c = csr[p + 8 + g];
        int2 d = csr[p + 12 + g];
        float4 xa = *(const float4*)(x + (size_t)a.x * DIM + sl * 4);
        float4 xb = *(const float4*)(x + (size_t)b.x * DIM + sl * 4);
        float4 xc = *(const float4*)(x + (size_t)c.x * DIM + sl * 4);
        float4 xd = *(const float4*)(x + (size_t)d.x * DIM + sl * 4);
        float va = __int_as_float(a.y), vb = __int_as_float(b.y);
        float vc = __int_as_float(c.y), vd = __int_as_float(d.y);
        acc.x += va * xa.x; acc.y += va * xa.y; acc.z += va * xa.z; acc.w += va * xa.w;
        acc.x += vb * xb.x; acc.y += vb * xb.y; acc.z += vb * xb.z; acc.w += vb * xb.w;
        acc.x += vc * xc.x; acc.y += vc * xc.y; acc.z += vc * xc.z; acc.w += vc * xc.w;
        acc.x += vd * xd.x; acc.y += vd * xd.y; acc.z += vd * xd.z; acc.w += vd * xd.w;
    }
    for (; p + 8 <= p1; p += 8) {
        int2 a = csr[p + g];
        int2 b = csr[p + 4 + g];
        float4 xa = *(const float4*)(x + (size_t)a.x * DIM + sl * 4);
        float4 xb = *(const float4*)(x + (size_t)b.x * DIM + sl * 4);
        float va = __int_as_float(a.y), vb = __int_as_float(b.y);
        acc.x += va * xa.x; acc.y += va * xa.y; acc.z += va * xa.z; acc.w += va * xa.w;
        acc.x += vb * xb.x; acc.y += vb * xb.y; acc.z += vb * xb.z; acc.w += vb * xb.w;
    }
    for (; p < p1; p += 4) {
        int pe = p + g;
        if (pe < p1) {
            int2 a = csr[pe];
            float4 xa = *(const float4*)(x + (size_t)a.x * DIM + sl * 4);
            float va = __int_as_float(a.y);
            acc.x += va * xa.x; acc.y += va * xa.y; acc.z += va * xa.z; acc.w += va * xa.w;
        }
    }
#pragma unroll
    for (int m = 16; m <= 32; m <<= 1) {
        acc.x += __shfl_xor(acc.x, m);
        acc.y += __shfl_xor(acc.y, m);
        acc.z += __shfl_xor(acc.z, m);
        acc.w += __shfl_xor(acc.w, m);
    }
    if (lane < 16) *(float4*)(agg + (size_t)row * DIM + lane * 4) = acc;
}

// ---------------- Dense layer: lane = node, registers = accumulators ----------------
// y[n][d] = leaky( s1[d] + b1[d] + agg[n][d]*(s2[d] + b2[d]) )
// s1[d] = sum_j (x+agg)[n][j] * w1T[j][d];  s2[d] = sum_j x[n][j] * w2T[j][d]
// Wave w: nodes [blk*128 + (w>>1)*64 + lane], dims [(w&1)*32, +32).

__global__ __launch_bounds__(256) void dense_kernel(const float* __restrict__ x,
                                                    const float* __restrict__ agg,
                                                    const float* __restrict__ w1T,
                                                    const float* __restrict__ w2T,
                                                    const float* __restrict__ b1,
                                                    const float* __restrict__ b2,
                                                    float* __restrict__ y) {
    int lane = threadIdx.x & 63;
    int wave = threadIdx.x >> 6;
    int node = blockIdx.x * 128 + ((wave >> 1) << 6) + lane;
    int d0 = (wave & 1) << 5;
    bool valid = node < N_NODES;
    int nc = valid ? node : (N_NODES - 1);
    const float* xrow = x + (size_t)nc * DIM;
    const float* arow = agg + (size_t)nc * DIM;

    float s1[32] = {};
    float s2[32] = {};

    for (int jq = 0; jq < 16; ++jq) {
        float4 xc4 = *(const float4*)(xrow + jq * 4);
        float4 xa4 = *(const float4*)(arow + jq * 4);
        float xcv[4] = {xc4.x, xc4.y, xc4.z, xc4.w};
        float xsv[4] = {xc4.x + xa4.x, xc4.y + xa4.y, xc4.z + xa4.z, xc4.w + xa4.w};
#pragma unroll
        for (int sub = 0; sub < 4; ++sub) {
            const float* w1r = w1T + (size_t)(jq * 4 + sub) * 64 + d0;
            const float* w2r = w2T + (size_t)(jq * 4 + sub) * 64 + d0;
            float xs = xsv[sub], xc = xcv[sub];
#pragma unroll
            for (int dc = 0; dc < 8; ++dc) {
                float4 wa = *(const float4*)(w1r + dc * 4);
                float4 wb = *(const float4*)(w2r + dc * 4);
                s1[dc * 4 + 0] += wa.x * xs;
                s1[dc * 4 + 1] += wa.y * xs;
                s1[dc * 4 + 2] += wa.z * xs;
                s1[dc * 4 + 3] += wa.w * xs;
                s2[dc * 4 + 0] += wb.x * xc;
                s2[dc * 4 + 1] += wb.y * xc;
                s2[dc * 4 + 2] += wb.z * xc;
                s2[dc * 4 + 3] += wb.w * xc;
            }
        }
    }

#pragma unroll
    for (int dc = 0; dc < 8; ++dc) {
        float4 xa4 = *(const float4*)(arow + d0 + dc * 4);
        float4 bv1 = *(const float4*)(b1 + d0 + dc * 4);
        float4 bv2 = *(const float4*)(b2 + d0 + dc * 4);
        float4 o;
        float t;
        t = s1[dc * 4 + 0] + bv1.x + xa4.x * (s2[dc * 4 + 0] + bv2.x);
        o.x = (t > 0.f) ? t : 0.01f * t;
        t = s1[dc * 4 + 1] + bv1.y + xa4.y * (s2[dc * 4 + 1] + bv2.y);
        o.y = (t > 0.f) ? t : 0.01f * t;
        t = s1[dc * 4 + 2] + bv1.z + xa4.z * (s2[dc * 4 + 2] + bv2.z);
        o.z = (t > 0.f) ? t : 0.01f * t;
        t = s1[dc * 4 + 3] + bv1.w + xa4.w * (s2[dc * 4 + 3] + bv2.w);
        o.w = (t > 0.f) ? t : 0.01f * t;
        if (valid) *(float4*)(y + (size_t)node * DIM + d0 + dc * 4) = o;
    }
}

// ---------------- Per-layer dot contributions ----------------

__global__ __launch_bounds__(256) void gather_dots_kernel(const float* __restrict__ x,
                                                          const int* __restrict__ user,
                                                          const int* __restrict__ pos,
                                                          const int* __restrict__ neg,
                                                          float* __restrict__ dst) {
    int lane = threadIdx.x & 63;
    int i = blockIdx.x * 4 + (threadIdx.x >> 6);
    if (i >= BATCH) return;
    int ui = user[i], pi = pos[i], ni = neg[i];
    float u = x[(size_t)ui * DIM + lane];
    float p = x[(size_t)pi * DIM + lane];
    float n = x[(size_t)ni * DIM + lane];
    float v = u * (p - n);
#pragma unroll
    for (int off = 32; off; off >>= 1) v += __shfl_xor(v, off);
    if (lane == 0) dst[i] = v;
}

// ---------------- Final loss ----------------

__global__ __launch_bounds__(1024) void loss_kernel(const float* __restrict__ dots,
                                                    float* __restrict__ out) {
    __shared__ float red[16];
    int tid = threadIdx.x;
    float acc = 0.f;
    for (int i = tid; i < BATCH; i += 1024) {
        float d = dots[i] + dots[BATCH + i] + dots[2 * BATCH + i] + dots[3 * BATCH + i];
        acc += fmaxf(-d, 0.f) + log1pf(expf(-fabsf(d)));
    }
#pragma unroll
    for (int off = 32; off; off >>= 1) acc += __shfl_xor(acc, off);
    if ((tid & 63) == 0) red[tid >> 6] = acc;
    __syncthreads();
    if (tid < 16) {
        float v = red[tid];
#pragma unroll
        for (int off = 8; off; off >>= 1) v += __shfl_xor(v, off);
        if (tid == 0) out[0] = v;
    }
}

// ---------------- Launch ----------------

extern "C" void kernel_launch(void* const* d_in, const int* in_sizes, int n_in,
                              void* d_out, int out_size, void* d_ws, size_t ws_size,
                              hipStream_t stream) {
    const float* emb  = (const float*)d_in[0];
    const float* w1_w = (const float*)d_in[1];
    const float* w1_b = (const float*)d_in[2];
    const float* w2_w = (const float*)d_in[3];
    const float* w2_b = (const float*)d_in[4];
    const float* vals = (const float*)d_in[5];
    const int* rows = (const int*)d_in[6];
    const int* cols = (const int*)d_in[7];
    const int* user = (const int*)d_in[8];
    const int* pos  = (const int*)d_in[9];
    const int* neg  = (const int*)d_in[10];
    float* out = (float*)d_out;

    char* w = (char*)d_ws;
    float* bufA = (float*)w;  w += (size_t)N_NODES * DIM * 4;   // also CSR staging
    float* bufB = (float*)w;  w += (size_t)N_NODES * DIM * 4;
    float* agg  = (float*)w;  w += (size_t)N_NODES * DIM * 4;
    int* row_ptr = (int*)w;   w += (((size_t)(N_NODES + 1) * 4) + 255) / 256 * 256;
    int2* csr    = (int2*)w;  w += (size_t)EDGES * 8;
    int* bhist   = (int*)w;   w += (size_t)NBUCK * NABLK * 4;
    int* boffs   = (int*)w;   w += (size_t)NBUCK * NABLK * 4;
    float* dots  = (float*)w; w += (size_t)4 * BATCH * 4;
    float* w1T   = (float*)w; w += (size_t)NLAYER * DIM * DIM * 4;
    float* w2T   = (float*)w; w += (size_t)NLAYER * DIM * DIM * 4;

    int2* staging = (int2*)bufA;

    bucket_hist_kernel<<<NABLK, 256, 0, stream>>>(rows, bhist);
    bucket_scan_kernel<<<1, 1024, 0, stream>>>(bhist, boffs);
    bucket_scatter_kernel<<<NABLK, 256, 0, stream>>>(rows, cols, vals, boffs, staging);
    csr_build_kernel<<<NBUCK, 256, 0, stream>>>(boffs, staging, row_ptr, csr);

    transpose_w_kernel<<<(NLAYER * DIM * DIM + 255) / 256, 256, 0, stream>>>(w1_w, w2_w, w1T, w2T);

    gather_dots_kernel<<<BATCH / 4, 256, 0, stream>>>(emb, user, pos, neg, dots);

    const float* x = emb;
    float* bufs[2] = {bufA, bufB};
    for (int l = 0; l < NLAYER; ++l) {
        float* y = bufs[l & 1];
        spmm_kernel<<<(N_NODES + 3) / 4, 256, 0, stream>>>(row_ptr, csr, x, agg);
        dense_kernel<<<(N_NODES + 127) / 128, 256, 0, stream>>>(
            x, agg,
            w1T + (size_t)l * DIM * DIM, w2T + (size_t)l * DIM * DIM,
            w1_b + (size_t)l * DIM, w2_b + (size_t)l * DIM,
            y);
        gather_dots_kernel<<<BATCH / 4, 256, 0, stream>>>(y, user, pos, neg,
                                                          dots + (size_t)(l + 1) * BATCH);
        x = y;
    }

    loss_kernel<<<1, 1024, 0, stream>>>(dots, out);
}